// Round 3
// baseline (217.319 us; speedup 1.0000x reference)
//
#include <hip/hip_runtime.h>
#include <math.h>

// NormalMixtureEM: B=16384 rows, L=512, K=4, 5 EM iters. One wave per row.
// R7 (occupancy + LDS-pipe removal; R6 measured em ~74us, VALUBusy ~86% at
// OccupancyPercent ~53% == 4 blocks/CU == the __launch_bounds__ 2nd arg):
//  - __launch_bounds__(256, 8): hypothesis test that the waves-per-EU hint
//    was capping residency at 4 blocks/CU. VGPR=48 <= 64 so 8 waves/SIMD fit;
//    grid 4096 blocks = 2 rounds at 8/CU. Expect the ~14% VALU idle (trans
//    latency + lgkm waits not hidden by 4 waves) to shrink.
//  - All ds_swizzle uses were intra-quad -> replaced with DPP quad_perm on
//    the VALU pipe (no LDS traffic, no lgkmcnt waits):
//      component-3 broadcast  = quad_perm:[3,3,3,3] (ctrl 0xFF)
//      butterfly xor1 / xor2  = quad_perm:[1,0,3,2] / [2,3,0,1] (0xB1/0x4E)
//    Builtin-generated DPP lets the compiler insert hazard nops.
//  - g-store bases hoisted: two base pointers + constant <=4KB immediate
//    offsets replace per-store 64-bit address arithmetic.
//  - Kept: lane-per-component M-step (kk=lane&3), ratio softmax vs comp 3
//    (3 exp2 + 1 rcp / sample), wred3 interleaved DPP wave reduction,
//    float4 loads, iteration-invariant W{0,1,2} deriving comp-3 moments.

constexpr int Bn = 16384;
constexpr int Ln = 512;
constexpr int Kn = 4;
constexpr int NITER = 5;
constexpr float EPSf = 1e-8f;
constexpr float NOISEf = 0.01f;
constexpr float LOG2E = 1.4426950408889634f;

__device__ __forceinline__ float frcp(float v) { return __builtin_amdgcn_rcpf(v); }
__device__ __forceinline__ float fexp2(float v) { return __builtin_amdgcn_exp2f(v); }

__device__ __forceinline__ float rlane(float v, int l) {
    return __int_as_float(__builtin_amdgcn_readlane(__float_as_int(v), l));
}

// DPP helpers (VALU pipe; compiler inserts any required hazard wait-states).
// quad_perm ctrl byte = sel0 | sel1<<2 | sel2<<4 | sel3<<6.
template <int CTRL>
__device__ __forceinline__ float dpp_mov(float v) {
    return __int_as_float(
        __builtin_amdgcn_update_dpp(0, __float_as_int(v), CTRL, 0xF, 0xF, true));
}
template <int CTRL>
__device__ __forceinline__ float dpp_add(float v) {
    return v + dpp_mov<CTRL>(v);
}

// Three interleaved full-wave sums via DPP adds; totals land in lane 63.
// Round-robin keeps same-register DPP reads 3 instrs apart (hazard-free);
// s_nop 1 guards the asm boundaries.
#define WRED3_STEP(ctrl) \
    "v_add_f32_dpp %0, %0, %0 " ctrl " row_mask:0xf bank_mask:0xf bound_ctrl:0\n\t" \
    "v_add_f32_dpp %1, %1, %1 " ctrl " row_mask:0xf bank_mask:0xf bound_ctrl:0\n\t" \
    "v_add_f32_dpp %2, %2, %2 " ctrl " row_mask:0xf bank_mask:0xf bound_ctrl:0\n\t"

__device__ __forceinline__ void wred3(float& a, float& b, float& c) {
    asm volatile(
        "s_nop 1\n\t"
        WRED3_STEP("row_shr:1")
        WRED3_STEP("row_shr:2")
        WRED3_STEP("row_shr:4")
        WRED3_STEP("row_shr:8")
        WRED3_STEP("row_bcast:15")
        WRED3_STEP("row_bcast:31")
        "s_nop 1"
        : "+v"(a), "+v"(b), "+v"(c));
}

struct RowState {
    float x[8], xx[8], wl[8];
    float muk, wk, invsek, sigk;   // per-lane component k = lane&3
    float mean, prior_var, blender, prior_p;
    float bm, bv;                  // (1-blender)*mean, (1-blender)*prior_var
    float W0, W1, W2;              // iteration-invariant: sum_l wl*{1, x, x^2}
};

template <bool LAST>
__device__ __forceinline__ void em_iter(RowState& st, float* __restrict__ gp0,
                                        int kk) {
    // Per-lane (k = kk) quadratic coefficients in log2 domain.
    float is2 = st.invsek * st.invsek;
    float lw2 = __log2f((st.wk + EPSf) * st.invsek);
    float Ak = (-0.5f * LOG2E) * is2;
    float Bk = (LOG2E * st.muk) * is2;
    float Ck = fmaf((-0.5f * LOG2E) * (st.muk * st.muk), is2, lw2);
    // Deltas vs component 3 (quad-lane 3) via DPP broadcast; lane kk==3 -> 0.
    float dAl = Ak - dpp_mov<0xFF>(Ak);
    float dBl = Bk - dpp_mov<0xFF>(Bk);
    float dCl = Ck - dpp_mov<0xFF>(Ck);
    // Gather the 9 wave-uniform coefficients into SGPRs.
    float a0 = rlane(dAl, 0), a1 = rlane(dAl, 1), a2 = rlane(dAl, 2);
    float b0 = rlane(dBl, 0), b1 = rlane(dBl, 1), b2 = rlane(dBl, 2);
    float c0 = rlane(dCl, 0), c1 = rlane(dCl, 1), c2 = rlane(dCl, 2);

    float S00 = 0, S01 = 0, S02 = 0;
    float S10 = 0, S11 = 0, S12 = 0;
    float S20 = 0, S21 = 0, S22 = 0;
#pragma unroll
    for (int j = 0; j < 8; ++j) {
        float lm0 = fmaf(a0, st.xx[j], fmaf(b0, st.x[j], c0));
        float lm1 = fmaf(a1, st.xx[j], fmaf(b1, st.x[j], c1));
        float lm2 = fmaf(a2, st.xx[j], fmaf(b2, st.x[j], c2));
        float r0 = fexp2(lm0);
        float r1 = fexp2(lm1);
        float r2 = fexp2(lm2);
        float esum = (r0 + r1) + (r2 + 1.f);   // component 3's ratio is 1
        float inv = frcp(esum);
        float wls = st.wl[j] * inv;
        float wlsx = wls * st.x[j];
        float wlsxx = wls * st.xx[j];
        S00 = fmaf(r0, wls, S00); S10 = fmaf(r0, wlsx, S10); S20 = fmaf(r0, wlsxx, S20);
        S01 = fmaf(r1, wls, S01); S11 = fmaf(r1, wlsx, S11); S21 = fmaf(r1, wlsxx, S21);
        S02 = fmaf(r2, wls, S02); S12 = fmaf(r2, wlsx, S12); S22 = fmaf(r2, wlsxx, S22);
        if (LAST) {
            float4 g4 = make_float4(r0 * inv, r1 * inv, r2 * inv, inv);
            if (j < 4) *(float4*)(gp0 + 4 * j) = g4;
            else       *(float4*)(gp0 + 1024 + 4 * (j - 4)) = g4;
        }
    }

    // Wave-reduce the 9 moments; totals in lane 63 -> SGPRs.
    wred3(S00, S10, S20);
    wred3(S01, S11, S21);
    wred3(S02, S12, S22);
    float s00 = rlane(S00, 63), s10 = rlane(S10, 63), s20 = rlane(S20, 63);
    float s01 = rlane(S01, 63), s11 = rlane(S11, 63), s21 = rlane(S21, 63);
    float s02 = rlane(S02, 63), s12 = rlane(S12, 63), s22 = rlane(S22, 63);
    // Component 3 from iteration-invariant totals (sum_k g = 1).
    float d0 = st.W0 - s00 - s01 - s02;
    float d1 = st.W1 - s10 - s11 - s12;
    float d2 = st.W2 - s20 - s21 - s22;
    // Per-lane selection of this lane's component moments.
    float vT0 = (kk == 0) ? s00 : (kk == 1) ? s01 : (kk == 2) ? s02 : d0;
    float vT1 = (kk == 0) ? s10 : (kk == 1) ? s11 : (kk == 2) ? s12 : d1;
    float vT2 = (kk == 0) ? s20 : (kk == 1) ? s21 : (kk == 2) ? s22 : d2;

    // M-step, one component per lane. Single-pass moments:
    // sum wg*(x-mu)^2 = S2 - 2*mu*S1 + mu^2*S0.
    float sg = fmaxf(vT0, EPSf);
    float rsg = frcp(sg);
    float mun = fmaf(st.blender, vT1 * rsg, st.bm);
    float num = fmaf(mun * mun, vT0, fmaf(-2.f * mun, vT1, vT2));
    float dv = fmaxf(num * rsg, 0.f);
    float var = fmaf(st.blender, dv, st.bv);
    float sgn = sqrtf(var + EPSf);
    st.muk = mun;
    st.sigk = sgn;
    st.invsek = frcp(sgn + EPSf);
    float wn = sg + st.prior_p;
    // wsum over the 4-lane group via DPP quad_perm butterfly (VALU pipe).
    float ws = dpp_add<0xB1>(wn);   // quad_perm:[1,0,3,2]  (xor 1)
    ws = dpp_add<0x4E>(ws);         // quad_perm:[2,3,0,1]  (xor 2)
    st.wk = wn * frcp(ws);
}

__global__ __launch_bounds__(256, 8) void em_kernel(
    const float* __restrict__ windows,
    const float* __restrict__ centers,
    const float* __restrict__ scales,
    const float* __restrict__ iweights,
    const float* __restrict__ prior_p_param,
    const float* __restrict__ weights_param,
    const float* __restrict__ blend,
    const float* __restrict__ noise,
    float* __restrict__ out_g,
    float* __restrict__ out_w,
    float* __restrict__ out_mu,
    float* __restrict__ out_sigma)
{
    const int lane = threadIdx.x & 63;
    const int kk = lane & 3;
    const int b = blockIdx.x * 4 + (threadIdx.x >> 6);

    RowState st;
    const float* __restrict__ xr = windows + (size_t)b * Ln;
    const float4 q0 = *(const float4*)(xr + 4 * lane);
    const float4 q1 = *(const float4*)(xr + 256 + 4 * lane);
    st.x[0] = q0.x; st.x[1] = q0.y; st.x[2] = q0.z; st.x[3] = q0.w;
    st.x[4] = q1.x; st.x[5] = q1.y; st.x[6] = q1.z; st.x[7] = q1.w;

    const float4 e0 = *(const float4*)(weights_param + 4 * lane);
    const float4 e1 = *(const float4*)(weights_param + 256 + 4 * lane);
    st.wl[0] = __expf(e0.x); st.wl[1] = __expf(e0.y);
    st.wl[2] = __expf(e0.z); st.wl[3] = __expf(e0.w);
    st.wl[4] = __expf(e1.x); st.wl[5] = __expf(e1.y);
    st.wl[6] = __expf(e1.z); st.wl[7] = __expf(e1.w);

    // Row stats + iteration-invariant weighted totals.
    float s = 0.f, ss = 0.f, w0 = 0.f, w1 = 0.f, w2 = 0.f;
#pragma unroll
    for (int j = 0; j < 8; ++j) {
        st.xx[j] = st.x[j] * st.x[j];
        s += st.x[j];
        ss += st.xx[j];
        w0 += st.wl[j];
        w1 = fmaf(st.wl[j], st.x[j], w1);
        w2 = fmaf(st.wl[j], st.xx[j], w2);
    }
    float junk = 0.f;
    wred3(s, ss, w0);
    wred3(w1, w2, junk);
    s = rlane(s, 63);
    ss = rlane(ss, 63);
    st.W0 = rlane(w0, 63);
    st.W1 = rlane(w1, 63);
    st.W2 = rlane(w2, 63);

    st.mean = s * (1.0f / Ln);
    float var1 = fmaxf((ss - s * st.mean) * (1.0f / (Ln - 1)), 0.f);
    const float sd = sqrtf(var1);
    st.prior_var = var1;

    st.prior_p = 1.f / (1.f + __expf(-prior_p_param[0]));
    st.blender = 1.f / (1.f + __expf(-blend[0]));
    const float omb = 1.f - st.blender;
    st.bm = omb * st.mean;
    st.bv = omb * st.prior_var;

    // Per-lane component init (k = kk).
    st.muk = fmaf(centers[kk], sd, st.mean) + noise[(size_t)b * 4 + kk] * sd * NOISEf;
    float sg0 = fabsf(scales[kk]) * sd;
    st.sigk = sg0;
    st.wk = iweights[kk];
    st.invsek = frcp(sg0 + EPSf);

    // Hoisted g-store bases: sample (lane,j<4) -> l = 4*lane+j,
    // (lane,j>=4) -> l = 256+4*lane+(j-4); float offset = 4*l.
    float* gp0 = out_g + (size_t)b * (Ln * Kn) + 16 * lane;

    for (int it = 0; it < NITER - 1; ++it)
        em_iter<false>(st, gp0, kk);
    em_iter<true>(st, gp0, kk);

    if (lane < 4) {
        out_w[(size_t)b * 4 + lane]     = st.wk;
        out_mu[(size_t)b * 4 + lane]    = st.muk;
        out_sigma[(size_t)b * 4 + lane] = st.sigk;
    }
}

extern "C" void kernel_launch(void* const* d_in, const int* in_sizes, int n_in,
                              void* d_out, int out_size, void* d_ws, size_t ws_size,
                              hipStream_t stream) {
    const float* windows       = (const float*)d_in[0];
    const float* init_centers  = (const float*)d_in[1];
    const float* init_scales   = (const float*)d_in[2];
    const float* init_weights  = (const float*)d_in[3];
    const float* prior_p_param = (const float*)d_in[4];
    const float* weights_param = (const float*)d_in[5];
    const float* blend         = (const float*)d_in[6];
    const float* noise         = (const float*)d_in[7];

    float* out       = (float*)d_out;
    float* out_g     = out;                                    // [B, L, K]
    float* out_w     = out_g + (size_t)Bn * Ln * Kn;           // [B, K]
    float* out_mu    = out_w + (size_t)Bn * Kn;                // [B, K]
    float* out_sigma = out_mu + (size_t)Bn * Kn;               // [B, K]

    dim3 grid(Bn / 4);   // 4 waves per block, 1 wave per row
    dim3 block(256);
    hipLaunchKernelGGL(em_kernel, grid, block, 0, stream,
                       windows, init_centers, init_scales, init_weights,
                       prior_p_param, weights_param, blend, noise,
                       out_g, out_w, out_mu, out_sigma);
}

// Round 4
// 209.350 us; speedup vs baseline: 1.0381x; 1.0381x over previous
//
#include <hip/hip_runtime.h>
#include <math.h>

// NormalMixtureEM: B=16384 rows, L=512, K=4, 5 EM iters.
// R8 (spill revert + dual-row ILP):
//  - R7's __launch_bounds__(256,8) forced VGPR=32 -> RowState spilled to
//    scratch (FETCH 16.7->50MB, WRITE 131.8->205.9MB, VALUBusy 86->62%,
//    em 74->92us). Reverted to (256,4). Lesson: the 2nd arg is a MIN (it
//    only constrains regalloc); R6's 53% occupancy was latency, not a cap.
//  - TWO ROWS PER WAVE: two independent streams through the inner loop's
//    exp2->esum->rcp latency chains (the idle the extra waves couldn't hide),
//    and the row-invariant wl[8]=exp(weights_param), W0=sum(wl) computed once
//    per wave. Init reductions = wred6+wred3 (9 slots, none wasted);
//    per-iter 18 moments = 3x wred6.
//  - Kept from R6/R7: lane-per-component M-step (kk=lane&3), DPP quad_perm
//    for intra-quad shuffles, ratio softmax vs comp 3 (3 exp2 + 1 rcp per
//    sample), iteration-invariant W totals deriving comp-3 moments, float4
//    loads, hoisted g-store bases.

constexpr int Bn = 16384;
constexpr int Ln = 512;
constexpr int Kn = 4;
constexpr int NITER = 5;
constexpr float EPSf = 1e-8f;
constexpr float NOISEf = 0.01f;
constexpr float LOG2E = 1.4426950408889634f;

__device__ __forceinline__ float frcp(float v) { return __builtin_amdgcn_rcpf(v); }
__device__ __forceinline__ float fexp2(float v) { return __builtin_amdgcn_exp2f(v); }

__device__ __forceinline__ float rlane(float v, int l) {
    return __int_as_float(__builtin_amdgcn_readlane(__float_as_int(v), l));
}

// DPP helpers (VALU pipe; compiler inserts required hazard wait-states).
// quad_perm ctrl byte = sel0 | sel1<<2 | sel2<<4 | sel3<<6.
template <int CTRL>
__device__ __forceinline__ float dpp_mov(float v) {
    return __int_as_float(
        __builtin_amdgcn_update_dpp(0, __float_as_int(v), CTRL, 0xF, 0xF, true));
}
template <int CTRL>
__device__ __forceinline__ float dpp_add(float v) {
    return v + dpp_mov<CTRL>(v);
}

// Interleaved full-wave sums via DPP adds; totals land in lane 63.
// Round-robin keeps same-register DPP reads >=3 instrs apart (hazard-free);
// s_nop 1 guards the asm boundaries.
#define WRED3_STEP(ctrl) \
    "v_add_f32_dpp %0, %0, %0 " ctrl " row_mask:0xf bank_mask:0xf bound_ctrl:0\n\t" \
    "v_add_f32_dpp %1, %1, %1 " ctrl " row_mask:0xf bank_mask:0xf bound_ctrl:0\n\t" \
    "v_add_f32_dpp %2, %2, %2 " ctrl " row_mask:0xf bank_mask:0xf bound_ctrl:0\n\t"

__device__ __forceinline__ void wred3(float& a, float& b, float& c) {
    asm volatile(
        "s_nop 1\n\t"
        WRED3_STEP("row_shr:1")
        WRED3_STEP("row_shr:2")
        WRED3_STEP("row_shr:4")
        WRED3_STEP("row_shr:8")
        WRED3_STEP("row_bcast:15")
        WRED3_STEP("row_bcast:31")
        "s_nop 1"
        : "+v"(a), "+v"(b), "+v"(c));
}

#define WRED6_STEP(ctrl) \
    "v_add_f32_dpp %0, %0, %0 " ctrl " row_mask:0xf bank_mask:0xf bound_ctrl:0\n\t" \
    "v_add_f32_dpp %1, %1, %1 " ctrl " row_mask:0xf bank_mask:0xf bound_ctrl:0\n\t" \
    "v_add_f32_dpp %2, %2, %2 " ctrl " row_mask:0xf bank_mask:0xf bound_ctrl:0\n\t" \
    "v_add_f32_dpp %3, %3, %3 " ctrl " row_mask:0xf bank_mask:0xf bound_ctrl:0\n\t" \
    "v_add_f32_dpp %4, %4, %4 " ctrl " row_mask:0xf bank_mask:0xf bound_ctrl:0\n\t" \
    "v_add_f32_dpp %5, %5, %5 " ctrl " row_mask:0xf bank_mask:0xf bound_ctrl:0\n\t"

__device__ __forceinline__ void wred6(float& a, float& b, float& c,
                                      float& d, float& e, float& f) {
    asm volatile(
        "s_nop 1\n\t"
        WRED6_STEP("row_shr:1")
        WRED6_STEP("row_shr:2")
        WRED6_STEP("row_shr:4")
        WRED6_STEP("row_shr:8")
        WRED6_STEP("row_bcast:15")
        WRED6_STEP("row_bcast:31")
        "s_nop 1"
        : "+v"(a), "+v"(b), "+v"(c), "+v"(d), "+v"(e), "+v"(f));
}

struct Row {
    float x[8], xx[8];
    float muk, wk, invsek, sigk;   // per-lane component k = lane&3
    float W1, W2;                  // sum_l wl*{x, x^2} (iteration-invariant)
    float bm, bv;                  // (1-blender)*mean, (1-blender)*prior_var
};

// Per-row coefficient prep: per-lane quadratic in log2 domain, deltas vs
// component 3 (quad-lane 3), gathered to 9 wave-uniform scalars.
__device__ __forceinline__ void coeffs(const Row& R,
        float& a0, float& a1, float& a2,
        float& b0, float& b1, float& b2,
        float& c0, float& c1, float& c2) {
    float is2 = R.invsek * R.invsek;
    float lw2 = __log2f((R.wk + EPSf) * R.invsek);
    float Ak = (-0.5f * LOG2E) * is2;
    float Bk = (LOG2E * R.muk) * is2;
    float Ck = fmaf((-0.5f * LOG2E) * (R.muk * R.muk), is2, lw2);
    float dAl = Ak - dpp_mov<0xFF>(Ak);
    float dBl = Bk - dpp_mov<0xFF>(Bk);
    float dCl = Ck - dpp_mov<0xFF>(Ck);
    a0 = rlane(dAl, 0); a1 = rlane(dAl, 1); a2 = rlane(dAl, 2);
    b0 = rlane(dBl, 0); b1 = rlane(dBl, 1); b2 = rlane(dBl, 2);
    c0 = rlane(dCl, 0); c1 = rlane(dCl, 1); c2 = rlane(dCl, 2);
}

// Per-row M-step from gathered moments (one component per lane).
__device__ __forceinline__ void mstep(Row& R, float blender, float prior_p,
        float W0,
        float s00, float s01, float s02,
        float s10, float s11, float s12,
        float s20, float s21, float s22, int kk) {
    float d0 = W0 - s00 - s01 - s02;
    float d1 = R.W1 - s10 - s11 - s12;
    float d2 = R.W2 - s20 - s21 - s22;
    float vT0 = (kk == 0) ? s00 : (kk == 1) ? s01 : (kk == 2) ? s02 : d0;
    float vT1 = (kk == 0) ? s10 : (kk == 1) ? s11 : (kk == 2) ? s12 : d1;
    float vT2 = (kk == 0) ? s20 : (kk == 1) ? s21 : (kk == 2) ? s22 : d2;
    float sg = fmaxf(vT0, EPSf);
    float rsg = frcp(sg);
    float mun = fmaf(blender, vT1 * rsg, R.bm);
    float num = fmaf(mun * mun, vT0, fmaf(-2.f * mun, vT1, vT2));
    float dv = fmaxf(num * rsg, 0.f);
    float var = fmaf(blender, dv, R.bv);
    float sgn = sqrtf(var + EPSf);
    R.muk = mun;
    R.sigk = sgn;
    R.invsek = frcp(sgn + EPSf);
    float wn = sg + prior_p;
    float ws = dpp_add<0xB1>(wn);   // quad_perm:[1,0,3,2]  (xor 1)
    ws = dpp_add<0x4E>(ws);         // quad_perm:[2,3,0,1]  (xor 2)
    R.wk = wn * frcp(ws);
}

template <bool LAST>
__device__ __forceinline__ void em_iter2(Row& A, Row& B, const float wl[8],
        float W0, float blender, float prior_p,
        float* __restrict__ gpA, float* __restrict__ gpB, int kk) {
    float a0A, a1A, a2A, b0A, b1A, b2A, c0A, c1A, c2A;
    float a0B, a1B, a2B, b0B, b1B, b2B, c0B, c1B, c2B;
    coeffs(A, a0A, a1A, a2A, b0A, b1A, b2A, c0A, c1A, c2A);
    coeffs(B, a0B, a1B, a2B, b0B, b1B, b2B, c0B, c1B, c2B);

    float SA00 = 0, SA01 = 0, SA02 = 0, SA10 = 0, SA11 = 0, SA12 = 0,
          SA20 = 0, SA21 = 0, SA22 = 0;
    float SB00 = 0, SB01 = 0, SB02 = 0, SB10 = 0, SB11 = 0, SB12 = 0,
          SB20 = 0, SB21 = 0, SB22 = 0;
#pragma unroll
    for (int j = 0; j < 8; ++j) {
        // Row A
        float lmA0 = fmaf(a0A, A.xx[j], fmaf(b0A, A.x[j], c0A));
        float lmA1 = fmaf(a1A, A.xx[j], fmaf(b1A, A.x[j], c1A));
        float lmA2 = fmaf(a2A, A.xx[j], fmaf(b2A, A.x[j], c2A));
        float rA0 = fexp2(lmA0);
        float rA1 = fexp2(lmA1);
        float rA2 = fexp2(lmA2);
        // Row B (independent stream interleaves with A's trans latency)
        float lmB0 = fmaf(a0B, B.xx[j], fmaf(b0B, B.x[j], c0B));
        float lmB1 = fmaf(a1B, B.xx[j], fmaf(b1B, B.x[j], c1B));
        float lmB2 = fmaf(a2B, B.xx[j], fmaf(b2B, B.x[j], c2B));
        float rB0 = fexp2(lmB0);
        float rB1 = fexp2(lmB1);
        float rB2 = fexp2(lmB2);

        float esA = (rA0 + rA1) + (rA2 + 1.f);
        float invA = frcp(esA);
        float esB = (rB0 + rB1) + (rB2 + 1.f);
        float invB = frcp(esB);

        float wlsA = wl[j] * invA;
        float wlsxA = wlsA * A.x[j];
        float wlsxxA = wlsA * A.xx[j];
        SA00 = fmaf(rA0, wlsA, SA00); SA10 = fmaf(rA0, wlsxA, SA10); SA20 = fmaf(rA0, wlsxxA, SA20);
        SA01 = fmaf(rA1, wlsA, SA01); SA11 = fmaf(rA1, wlsxA, SA11); SA21 = fmaf(rA1, wlsxxA, SA21);
        SA02 = fmaf(rA2, wlsA, SA02); SA12 = fmaf(rA2, wlsxA, SA12); SA22 = fmaf(rA2, wlsxxA, SA22);

        float wlsB = wl[j] * invB;
        float wlsxB = wlsB * B.x[j];
        float wlsxxB = wlsB * B.xx[j];
        SB00 = fmaf(rB0, wlsB, SB00); SB10 = fmaf(rB0, wlsxB, SB10); SB20 = fmaf(rB0, wlsxxB, SB20);
        SB01 = fmaf(rB1, wlsB, SB01); SB11 = fmaf(rB1, wlsxB, SB11); SB21 = fmaf(rB1, wlsxxB, SB21);
        SB02 = fmaf(rB2, wlsB, SB02); SB12 = fmaf(rB2, wlsxB, SB12); SB22 = fmaf(rB2, wlsxxB, SB22);

        if (LAST) {
            float4 gA = make_float4(rA0 * invA, rA1 * invA, rA2 * invA, invA);
            float4 gB = make_float4(rB0 * invB, rB1 * invB, rB2 * invB, invB);
            if (j < 4) {
                *(float4*)(gpA + 4 * j) = gA;
                *(float4*)(gpB + 4 * j) = gB;
            } else {
                *(float4*)(gpA + 1024 + 4 * (j - 4)) = gA;
                *(float4*)(gpB + 1024 + 4 * (j - 4)) = gB;
            }
        }
    }

    // Wave-reduce the 18 moments; totals in lane 63 -> scalars.
    wred6(SA00, SA10, SA20, SB00, SB10, SB20);
    wred6(SA01, SA11, SA21, SB01, SB11, SB21);
    wred6(SA02, SA12, SA22, SB02, SB12, SB22);
    float sA00 = rlane(SA00, 63), sA10 = rlane(SA10, 63), sA20 = rlane(SA20, 63);
    float sA01 = rlane(SA01, 63), sA11 = rlane(SA11, 63), sA21 = rlane(SA21, 63);
    float sA02 = rlane(SA02, 63), sA12 = rlane(SA12, 63), sA22 = rlane(SA22, 63);
    float sB00 = rlane(SB00, 63), sB10 = rlane(SB10, 63), sB20 = rlane(SB20, 63);
    float sB01 = rlane(SB01, 63), sB11 = rlane(SB11, 63), sB21 = rlane(SB21, 63);
    float sB02 = rlane(SB02, 63), sB12 = rlane(SB12, 63), sB22 = rlane(SB22, 63);

    mstep(A, blender, prior_p, W0, sA00, sA01, sA02, sA10, sA11, sA12,
          sA20, sA21, sA22, kk);
    mstep(B, blender, prior_p, W0, sB00, sB01, sB02, sB10, sB11, sB12,
          sB20, sB21, sB22, kk);
}

__global__ __launch_bounds__(256, 4) void em_kernel(
    const float* __restrict__ windows,
    const float* __restrict__ centers,
    const float* __restrict__ scales,
    const float* __restrict__ iweights,
    const float* __restrict__ prior_p_param,
    const float* __restrict__ weights_param,
    const float* __restrict__ blend,
    const float* __restrict__ noise,
    float* __restrict__ out_g,
    float* __restrict__ out_w,
    float* __restrict__ out_mu,
    float* __restrict__ out_sigma)
{
    const int lane = threadIdx.x & 63;
    const int kk = lane & 3;
    const int b0 = blockIdx.x * 8 + (threadIdx.x >> 6) * 2;   // rows b0, b0+1

    // Row-invariant: wl = exp(weights_param), W0 = sum(wl).
    float wl[8];
    {
        const float4 e0 = *(const float4*)(weights_param + 4 * lane);
        const float4 e1 = *(const float4*)(weights_param + 256 + 4 * lane);
        wl[0] = __expf(e0.x); wl[1] = __expf(e0.y);
        wl[2] = __expf(e0.z); wl[3] = __expf(e0.w);
        wl[4] = __expf(e1.x); wl[5] = __expf(e1.y);
        wl[6] = __expf(e1.z); wl[7] = __expf(e1.w);
    }

    Row A, B;
    {
        const float* __restrict__ xa = windows + (size_t)b0 * Ln;
        const float4 qa0 = *(const float4*)(xa + 4 * lane);
        const float4 qa1 = *(const float4*)(xa + 256 + 4 * lane);
        A.x[0] = qa0.x; A.x[1] = qa0.y; A.x[2] = qa0.z; A.x[3] = qa0.w;
        A.x[4] = qa1.x; A.x[5] = qa1.y; A.x[6] = qa1.z; A.x[7] = qa1.w;
        const float* __restrict__ xb = xa + Ln;
        const float4 qb0 = *(const float4*)(xb + 4 * lane);
        const float4 qb1 = *(const float4*)(xb + 256 + 4 * lane);
        B.x[0] = qb0.x; B.x[1] = qb0.y; B.x[2] = qb0.z; B.x[3] = qb0.w;
        B.x[4] = qb1.x; B.x[5] = qb1.y; B.x[6] = qb1.z; B.x[7] = qb1.w;
    }

    // Row stats + iteration-invariant weighted totals (w0 shared).
    float sA = 0.f, ssA = 0.f, w1A = 0.f, w2A = 0.f;
    float sB = 0.f, ssB = 0.f, w1B = 0.f, w2B = 0.f;
    float w0 = 0.f;
#pragma unroll
    for (int j = 0; j < 8; ++j) {
        A.xx[j] = A.x[j] * A.x[j];
        B.xx[j] = B.x[j] * B.x[j];
        sA += A.x[j];  ssA += A.xx[j];
        sB += B.x[j];  ssB += B.xx[j];
        w0 += wl[j];
        w1A = fmaf(wl[j], A.x[j], w1A);  w2A = fmaf(wl[j], A.xx[j], w2A);
        w1B = fmaf(wl[j], B.x[j], w1B);  w2B = fmaf(wl[j], B.xx[j], w2B);
    }
    wred6(sA, ssA, w1A, w2A, sB, ssB);
    wred3(w1B, w2B, w0);
    sA = rlane(sA, 63);  ssA = rlane(ssA, 63);
    sB = rlane(sB, 63);  ssB = rlane(ssB, 63);
    A.W1 = rlane(w1A, 63);  A.W2 = rlane(w2A, 63);
    B.W1 = rlane(w1B, 63);  B.W2 = rlane(w2B, 63);
    const float W0 = rlane(w0, 63);

    const float prior_p = 1.f / (1.f + __expf(-prior_p_param[0]));
    const float blender = 1.f / (1.f + __expf(-blend[0]));
    const float omb = 1.f - blender;

    const float meanA = sA * (1.0f / Ln);
    const float varA = fmaxf((ssA - sA * meanA) * (1.0f / (Ln - 1)), 0.f);
    const float sdA = sqrtf(varA);
    A.bm = omb * meanA;
    A.bv = omb * varA;
    const float meanB = sB * (1.0f / Ln);
    const float varB = fmaxf((ssB - sB * meanB) * (1.0f / (Ln - 1)), 0.f);
    const float sdB = sqrtf(varB);
    B.bm = omb * meanB;
    B.bv = omb * varB;

    // Per-lane component init (k = kk).
    const float ck = centers[kk], sck = fabsf(scales[kk]), iwk = iweights[kk];
    A.muk = fmaf(ck, sdA, meanA) + noise[(size_t)b0 * 4 + kk] * sdA * NOISEf;
    B.muk = fmaf(ck, sdB, meanB) + noise[(size_t)(b0 + 1) * 4 + kk] * sdB * NOISEf;
    float sgA = sck * sdA, sgB = sck * sdB;
    A.sigk = sgA;  A.wk = iwk;  A.invsek = frcp(sgA + EPSf);
    B.sigk = sgB;  B.wk = iwk;  B.invsek = frcp(sgB + EPSf);

    // Hoisted g-store bases: sample (lane,j<4) -> l = 4*lane+j,
    // (lane,j>=4) -> l = 256+4*lane+(j-4); float offset = 4*l.
    float* gpA = out_g + (size_t)b0 * (Ln * Kn) + 16 * lane;
    float* gpB = gpA + Ln * Kn;

    for (int it = 0; it < NITER - 1; ++it)
        em_iter2<false>(A, B, wl, W0, blender, prior_p, gpA, gpB, kk);
    em_iter2<true>(A, B, wl, W0, blender, prior_p, gpA, gpB, kk);

    if (lane < 8) {
        // lanes 0..3 -> row A (kk=lane), lanes 4..7 -> row B (kk=lane-4);
        // (b0+1)*4 + (lane-4) == b0*4 + lane, so one flat index serves both.
        const size_t o = (size_t)b0 * 4 + lane;
        out_w[o]     = (lane < 4) ? A.wk : B.wk;
        out_mu[o]    = (lane < 4) ? A.muk : B.muk;
        out_sigma[o] = (lane < 4) ? A.sigk : B.sigk;
    }
}

extern "C" void kernel_launch(void* const* d_in, const int* in_sizes, int n_in,
                              void* d_out, int out_size, void* d_ws, size_t ws_size,
                              hipStream_t stream) {
    const float* windows       = (const float*)d_in[0];
    const float* init_centers  = (const float*)d_in[1];
    const float* init_scales   = (const float*)d_in[2];
    const float* init_weights  = (const float*)d_in[3];
    const float* prior_p_param = (const float*)d_in[4];
    const float* weights_param = (const float*)d_in[5];
    const float* blend         = (const float*)d_in[6];
    const float* noise         = (const float*)d_in[7];

    float* out       = (float*)d_out;
    float* out_g     = out;                                    // [B, L, K]
    float* out_w     = out_g + (size_t)Bn * Ln * Kn;           // [B, K]
    float* out_mu    = out_w + (size_t)Bn * Kn;                // [B, K]
    float* out_sigma = out_mu + (size_t)Bn * Kn;               // [B, K]

    dim3 grid(Bn / 8);   // 4 waves per block, 2 rows per wave
    dim3 block(256);
    hipLaunchKernelGGL(em_kernel, grid, block, 0, stream,
                       windows, init_centers, init_scales, init_weights,
                       prior_p_param, weights_param, blend, noise,
                       out_g, out_w, out_mu, out_sigma);
}

// Round 6
// 198.382 us; speedup vs baseline: 1.0955x; 1.0553x over previous
//
#include <hip/hip_runtime.h>
#include <math.h>

// NormalMixtureEM: B=16384 rows, L=512, K=4, 5 EM iters.
// R10 == R9 resubmitted verbatim (R9's bench failed at the container/broker
// level -- "MI355X container failed twice" -- before producing any kernel
// result; the source is structurally the verified R8 kernel with only the
// launch-bounds min-waves 4->2 and xx[] recompute changes).
// R9 (dual-row retry with register-pressure fix):
//  - R8's dual-row spilled: VGPR_Count=64 (exactly HALF the nominal
//    512/min_waves=128 budget; R7 showed 32 = half of 64). Theory: allocator
//    halves the unified gfx950 VGPR/AGPR budget for arch-VGPRs, and our
//    ~90 live values spilled to scratch (WRITE +51MB, em 95us).
//  - Fix 1: __launch_bounds__(256, 2) -> arch budget 128 by the observed
//    halving rule; ~85-95 live fits with headroom.
//  - Fix 2: dropped xx[8] arrays (-16 VGPR): recompute x*x per j in-loop.
//  - Kept from R8 (math verified correct there): two rows per wave for ILP
//    through the exp2->esum->rcp chains; row-invariant wl/W0 computed once;
//    wred6 paired reductions; lane-per-component M-step (kk=lane&3); DPP
//    quad_perm intra-quad shuffles; ratio softmax vs component 3; hoisted
//    g-store bases; float4 loads.

constexpr int Bn = 16384;
constexpr int Ln = 512;
constexpr int Kn = 4;
constexpr int NITER = 5;
constexpr float EPSf = 1e-8f;
constexpr float NOISEf = 0.01f;
constexpr float LOG2E = 1.4426950408889634f;

__device__ __forceinline__ float frcp(float v) { return __builtin_amdgcn_rcpf(v); }
__device__ __forceinline__ float fexp2(float v) { return __builtin_amdgcn_exp2f(v); }

__device__ __forceinline__ float rlane(float v, int l) {
    return __int_as_float(__builtin_amdgcn_readlane(__float_as_int(v), l));
}

// DPP helpers (VALU pipe; compiler inserts required hazard wait-states).
// quad_perm ctrl byte = sel0 | sel1<<2 | sel2<<4 | sel3<<6.
template <int CTRL>
__device__ __forceinline__ float dpp_mov(float v) {
    return __int_as_float(
        __builtin_amdgcn_update_dpp(0, __float_as_int(v), CTRL, 0xF, 0xF, true));
}
template <int CTRL>
__device__ __forceinline__ float dpp_add(float v) {
    return v + dpp_mov<CTRL>(v);
}

// Interleaved full-wave sums via DPP adds; totals land in lane 63.
// Round-robin keeps same-register DPP reads >=3 instrs apart (hazard-free);
// s_nop 1 guards the asm boundaries.
#define WRED3_STEP(ctrl) \
    "v_add_f32_dpp %0, %0, %0 " ctrl " row_mask:0xf bank_mask:0xf bound_ctrl:0\n\t" \
    "v_add_f32_dpp %1, %1, %1 " ctrl " row_mask:0xf bank_mask:0xf bound_ctrl:0\n\t" \
    "v_add_f32_dpp %2, %2, %2 " ctrl " row_mask:0xf bank_mask:0xf bound_ctrl:0\n\t"

__device__ __forceinline__ void wred3(float& a, float& b, float& c) {
    asm volatile(
        "s_nop 1\n\t"
        WRED3_STEP("row_shr:1")
        WRED3_STEP("row_shr:2")
        WRED3_STEP("row_shr:4")
        WRED3_STEP("row_shr:8")
        WRED3_STEP("row_bcast:15")
        WRED3_STEP("row_bcast:31")
        "s_nop 1"
        : "+v"(a), "+v"(b), "+v"(c));
}

#define WRED6_STEP(ctrl) \
    "v_add_f32_dpp %0, %0, %0 " ctrl " row_mask:0xf bank_mask:0xf bound_ctrl:0\n\t" \
    "v_add_f32_dpp %1, %1, %1 " ctrl " row_mask:0xf bank_mask:0xf bound_ctrl:0\n\t" \
    "v_add_f32_dpp %2, %2, %2 " ctrl " row_mask:0xf bank_mask:0xf bound_ctrl:0\n\t" \
    "v_add_f32_dpp %3, %3, %3 " ctrl " row_mask:0xf bank_mask:0xf bound_ctrl:0\n\t" \
    "v_add_f32_dpp %4, %4, %4 " ctrl " row_mask:0xf bank_mask:0xf bound_ctrl:0\n\t" \
    "v_add_f32_dpp %5, %5, %5 " ctrl " row_mask:0xf bank_mask:0xf bound_ctrl:0\n\t"

__device__ __forceinline__ void wred6(float& a, float& b, float& c,
                                      float& d, float& e, float& f) {
    asm volatile(
        "s_nop 1\n\t"
        WRED6_STEP("row_shr:1")
        WRED6_STEP("row_shr:2")
        WRED6_STEP("row_shr:4")
        WRED6_STEP("row_shr:8")
        WRED6_STEP("row_bcast:15")
        WRED6_STEP("row_bcast:31")
        "s_nop 1"
        : "+v"(a), "+v"(b), "+v"(c), "+v"(d), "+v"(e), "+v"(f));
}

struct Row {
    float x[8];
    float muk, wk, invsek, sigk;   // per-lane component k = lane&3
    float W1, W2;                  // sum_l wl*{x, x^2} (iteration-invariant)
    float bm, bv;                  // (1-blender)*mean, (1-blender)*prior_var
};

// Per-row coefficient prep: per-lane quadratic in log2 domain, deltas vs
// component 3 (quad-lane 3), gathered to 9 wave-uniform scalars.
__device__ __forceinline__ void coeffs(const Row& R,
        float& a0, float& a1, float& a2,
        float& b0, float& b1, float& b2,
        float& c0, float& c1, float& c2) {
    float is2 = R.invsek * R.invsek;
    float lw2 = __log2f((R.wk + EPSf) * R.invsek);
    float Ak = (-0.5f * LOG2E) * is2;
    float Bk = (LOG2E * R.muk) * is2;
    float Ck = fmaf((-0.5f * LOG2E) * (R.muk * R.muk), is2, lw2);
    float dAl = Ak - dpp_mov<0xFF>(Ak);
    float dBl = Bk - dpp_mov<0xFF>(Bk);
    float dCl = Ck - dpp_mov<0xFF>(Ck);
    a0 = rlane(dAl, 0); a1 = rlane(dAl, 1); a2 = rlane(dAl, 2);
    b0 = rlane(dBl, 0); b1 = rlane(dBl, 1); b2 = rlane(dBl, 2);
    c0 = rlane(dCl, 0); c1 = rlane(dCl, 1); c2 = rlane(dCl, 2);
}

// Per-row M-step from gathered moments (one component per lane).
__device__ __forceinline__ void mstep(Row& R, float blender, float prior_p,
        float W0,
        float s00, float s01, float s02,
        float s10, float s11, float s12,
        float s20, float s21, float s22, int kk) {
    float d0 = W0 - s00 - s01 - s02;
    float d1 = R.W1 - s10 - s11 - s12;
    float d2 = R.W2 - s20 - s21 - s22;
    float vT0 = (kk == 0) ? s00 : (kk == 1) ? s01 : (kk == 2) ? s02 : d0;
    float vT1 = (kk == 0) ? s10 : (kk == 1) ? s11 : (kk == 2) ? s12 : d1;
    float vT2 = (kk == 0) ? s20 : (kk == 1) ? s21 : (kk == 2) ? s22 : d2;
    float sg = fmaxf(vT0, EPSf);
    float rsg = frcp(sg);
    float mun = fmaf(blender, vT1 * rsg, R.bm);
    float num = fmaf(mun * mun, vT0, fmaf(-2.f * mun, vT1, vT2));
    float dv = fmaxf(num * rsg, 0.f);
    float var = fmaf(blender, dv, R.bv);
    float sgn = sqrtf(var + EPSf);
    R.muk = mun;
    R.sigk = sgn;
    R.invsek = frcp(sgn + EPSf);
    float wn = sg + prior_p;
    float ws = dpp_add<0xB1>(wn);   // quad_perm:[1,0,3,2]  (xor 1)
    ws = dpp_add<0x4E>(ws);         // quad_perm:[2,3,0,1]  (xor 2)
    R.wk = wn * frcp(ws);
}

template <bool LAST>
__device__ __forceinline__ void em_iter2(Row& A, Row& B, const float wl[8],
        float W0, float blender, float prior_p,
        float* __restrict__ gpA, float* __restrict__ gpB, int kk) {
    float a0A, a1A, a2A, b0A, b1A, b2A, c0A, c1A, c2A;
    float a0B, a1B, a2B, b0B, b1B, b2B, c0B, c1B, c2B;
    coeffs(A, a0A, a1A, a2A, b0A, b1A, b2A, c0A, c1A, c2A);
    coeffs(B, a0B, a1B, a2B, b0B, b1B, b2B, c0B, c1B, c2B);

    float SA00 = 0, SA01 = 0, SA02 = 0, SA10 = 0, SA11 = 0, SA12 = 0,
          SA20 = 0, SA21 = 0, SA22 = 0;
    float SB00 = 0, SB01 = 0, SB02 = 0, SB10 = 0, SB11 = 0, SB12 = 0,
          SB20 = 0, SB21 = 0, SB22 = 0;
#pragma unroll
    for (int j = 0; j < 8; ++j) {
        // x*x recomputed per row (1 v_mul) instead of a 16-reg xx[] array.
        float xA = A.x[j], xxA = xA * xA;
        float xB = B.x[j], xxB = xB * xB;
        // Row A
        float lmA0 = fmaf(a0A, xxA, fmaf(b0A, xA, c0A));
        float lmA1 = fmaf(a1A, xxA, fmaf(b1A, xA, c1A));
        float lmA2 = fmaf(a2A, xxA, fmaf(b2A, xA, c2A));
        float rA0 = fexp2(lmA0);
        float rA1 = fexp2(lmA1);
        float rA2 = fexp2(lmA2);
        // Row B (independent stream interleaves with A's trans latency)
        float lmB0 = fmaf(a0B, xxB, fmaf(b0B, xB, c0B));
        float lmB1 = fmaf(a1B, xxB, fmaf(b1B, xB, c1B));
        float lmB2 = fmaf(a2B, xxB, fmaf(b2B, xB, c2B));
        float rB0 = fexp2(lmB0);
        float rB1 = fexp2(lmB1);
        float rB2 = fexp2(lmB2);

        float esA = (rA0 + rA1) + (rA2 + 1.f);
        float invA = frcp(esA);
        float esB = (rB0 + rB1) + (rB2 + 1.f);
        float invB = frcp(esB);

        float wlsA = wl[j] * invA;
        float wlsxA = wlsA * xA;
        float wlsxxA = wlsA * xxA;
        SA00 = fmaf(rA0, wlsA, SA00); SA10 = fmaf(rA0, wlsxA, SA10); SA20 = fmaf(rA0, wlsxxA, SA20);
        SA01 = fmaf(rA1, wlsA, SA01); SA11 = fmaf(rA1, wlsxA, SA11); SA21 = fmaf(rA1, wlsxxA, SA21);
        SA02 = fmaf(rA2, wlsA, SA02); SA12 = fmaf(rA2, wlsxA, SA12); SA22 = fmaf(rA2, wlsxxA, SA22);

        float wlsB = wl[j] * invB;
        float wlsxB = wlsB * xB;
        float wlsxxB = wlsB * xxB;
        SB00 = fmaf(rB0, wlsB, SB00); SB10 = fmaf(rB0, wlsxB, SB10); SB20 = fmaf(rB0, wlsxxB, SB20);
        SB01 = fmaf(rB1, wlsB, SB01); SB11 = fmaf(rB1, wlsxB, SB11); SB21 = fmaf(rB1, wlsxxB, SB21);
        SB02 = fmaf(rB2, wlsB, SB02); SB12 = fmaf(rB2, wlsxB, SB12); SB22 = fmaf(rB2, wlsxxB, SB22);

        if (LAST) {
            float4 gA = make_float4(rA0 * invA, rA1 * invA, rA2 * invA, invA);
            float4 gB = make_float4(rB0 * invB, rB1 * invB, rB2 * invB, invB);
            if (j < 4) {
                *(float4*)(gpA + 4 * j) = gA;
                *(float4*)(gpB + 4 * j) = gB;
            } else {
                *(float4*)(gpA + 1024 + 4 * (j - 4)) = gA;
                *(float4*)(gpB + 1024 + 4 * (j - 4)) = gB;
            }
        }
    }

    // Wave-reduce the 18 moments; totals in lane 63 -> scalars.
    wred6(SA00, SA10, SA20, SB00, SB10, SB20);
    wred6(SA01, SA11, SA21, SB01, SB11, SB21);
    wred6(SA02, SA12, SA22, SB02, SB12, SB22);
    float sA00 = rlane(SA00, 63), sA10 = rlane(SA10, 63), sA20 = rlane(SA20, 63);
    float sA01 = rlane(SA01, 63), sA11 = rlane(SA11, 63), sA21 = rlane(SA21, 63);
    float sA02 = rlane(SA02, 63), sA12 = rlane(SA12, 63), sA22 = rlane(SA22, 63);
    float sB00 = rlane(SB00, 63), sB10 = rlane(SB10, 63), sB20 = rlane(SB20, 63);
    float sB01 = rlane(SB01, 63), sB11 = rlane(SB11, 63), sB21 = rlane(SB21, 63);
    float sB02 = rlane(SB02, 63), sB12 = rlane(SB12, 63), sB22 = rlane(SB22, 63);

    mstep(A, blender, prior_p, W0, sA00, sA01, sA02, sA10, sA11, sA12,
          sA20, sA21, sA22, kk);
    mstep(B, blender, prior_p, W0, sB00, sB01, sB02, sB10, sB11, sB12,
          sB20, sB21, sB22, kk);
}

__global__ __launch_bounds__(256, 2) void em_kernel(
    const float* __restrict__ windows,
    const float* __restrict__ centers,
    const float* __restrict__ scales,
    const float* __restrict__ iweights,
    const float* __restrict__ prior_p_param,
    const float* __restrict__ weights_param,
    const float* __restrict__ blend,
    const float* __restrict__ noise,
    float* __restrict__ out_g,
    float* __restrict__ out_w,
    float* __restrict__ out_mu,
    float* __restrict__ out_sigma)
{
    const int lane = threadIdx.x & 63;
    const int kk = lane & 3;
    const int b0 = blockIdx.x * 8 + (threadIdx.x >> 6) * 2;   // rows b0, b0+1

    // Row-invariant: wl = exp(weights_param), W0 = sum(wl).
    float wl[8];
    {
        const float4 e0 = *(const float4*)(weights_param + 4 * lane);
        const float4 e1 = *(const float4*)(weights_param + 256 + 4 * lane);
        wl[0] = __expf(e0.x); wl[1] = __expf(e0.y);
        wl[2] = __expf(e0.z); wl[3] = __expf(e0.w);
        wl[4] = __expf(e1.x); wl[5] = __expf(e1.y);
        wl[6] = __expf(e1.z); wl[7] = __expf(e1.w);
    }

    Row A, B;
    {
        const float* __restrict__ xa = windows + (size_t)b0 * Ln;
        const float4 qa0 = *(const float4*)(xa + 4 * lane);
        const float4 qa1 = *(const float4*)(xa + 256 + 4 * lane);
        A.x[0] = qa0.x; A.x[1] = qa0.y; A.x[2] = qa0.z; A.x[3] = qa0.w;
        A.x[4] = qa1.x; A.x[5] = qa1.y; A.x[6] = qa1.z; A.x[7] = qa1.w;
        const float* __restrict__ xb = xa + Ln;
        const float4 qb0 = *(const float4*)(xb + 4 * lane);
        const float4 qb1 = *(const float4*)(xb + 256 + 4 * lane);
        B.x[0] = qb0.x; B.x[1] = qb0.y; B.x[2] = qb0.z; B.x[3] = qb0.w;
        B.x[4] = qb1.x; B.x[5] = qb1.y; B.x[6] = qb1.z; B.x[7] = qb1.w;
    }

    // Row stats + iteration-invariant weighted totals (w0 shared).
    float sA = 0.f, ssA = 0.f, w1A = 0.f, w2A = 0.f;
    float sB = 0.f, ssB = 0.f, w1B = 0.f, w2B = 0.f;
    float w0 = 0.f;
#pragma unroll
    for (int j = 0; j < 8; ++j) {
        float xA = A.x[j], xxA = xA * xA;
        float xB = B.x[j], xxB = xB * xB;
        sA += xA;  ssA += xxA;
        sB += xB;  ssB += xxB;
        w0 += wl[j];
        w1A = fmaf(wl[j], xA, w1A);  w2A = fmaf(wl[j], xxA, w2A);
        w1B = fmaf(wl[j], xB, w1B);  w2B = fmaf(wl[j], xxB, w2B);
    }
    wred6(sA, ssA, w1A, w2A, sB, ssB);
    wred3(w1B, w2B, w0);
    sA = rlane(sA, 63);  ssA = rlane(ssA, 63);
    sB = rlane(sB, 63);  ssB = rlane(ssB, 63);
    A.W1 = rlane(w1A, 63);  A.W2 = rlane(w2A, 63);
    B.W1 = rlane(w1B, 63);  B.W2 = rlane(w2B, 63);
    const float W0 = rlane(w0, 63);

    const float prior_p = 1.f / (1.f + __expf(-prior_p_param[0]));
    const float blender = 1.f / (1.f + __expf(-blend[0]));
    const float omb = 1.f - blender;

    const float meanA = sA * (1.0f / Ln);
    const float varA = fmaxf((ssA - sA * meanA) * (1.0f / (Ln - 1)), 0.f);
    const float sdA = sqrtf(varA);
    A.bm = omb * meanA;
    A.bv = omb * varA;
    const float meanB = sB * (1.0f / Ln);
    const float varB = fmaxf((ssB - sB * meanB) * (1.0f / (Ln - 1)), 0.f);
    const float sdB = sqrtf(varB);
    B.bm = omb * meanB;
    B.bv = omb * varB;

    // Per-lane component init (k = kk).
    const float ck = centers[kk], sck = fabsf(scales[kk]), iwk = iweights[kk];
    A.muk = fmaf(ck, sdA, meanA) + noise[(size_t)b0 * 4 + kk] * sdA * NOISEf;
    B.muk = fmaf(ck, sdB, meanB) + noise[(size_t)(b0 + 1) * 4 + kk] * sdB * NOISEf;
    float sgA = sck * sdA, sgB = sck * sdB;
    A.sigk = sgA;  A.wk = iwk;  A.invsek = frcp(sgA + EPSf);
    B.sigk = sgB;  B.wk = iwk;  B.invsek = frcp(sgB + EPSf);

    // Hoisted g-store bases: sample (lane,j<4) -> l = 4*lane+j,
    // (lane,j>=4) -> l = 256+4*lane+(j-4); float offset = 4*l.
    float* gpA = out_g + (size_t)b0 * (Ln * Kn) + 16 * lane;
    float* gpB = gpA + Ln * Kn;

    if (lane < 8) {
        // placeholder to keep structure parallel; final writes below.
    }

    for (int it = 0; it < NITER - 1; ++it)
        em_iter2<false>(A, B, wl, W0, blender, prior_p, gpA, gpB, kk);
    em_iter2<true>(A, B, wl, W0, blender, prior_p, gpA, gpB, kk);

    if (lane < 8) {
        // lanes 0..3 -> row A (kk=lane), lanes 4..7 -> row B (kk=lane-4);
        // (b0+1)*4 + (lane-4) == b0*4 + lane, so one flat index serves both.
        const size_t o = (size_t)b0 * 4 + lane;
        out_w[o]     = (lane < 4) ? A.wk : B.wk;
        out_mu[o]    = (lane < 4) ? A.muk : B.muk;
        out_sigma[o] = (lane < 4) ? A.sigk : B.sigk;
    }
}

extern "C" void kernel_launch(void* const* d_in, const int* in_sizes, int n_in,
                              void* d_out, int out_size, void* d_ws, size_t ws_size,
                              hipStream_t stream) {
    const float* windows       = (const float*)d_in[0];
    const float* init_centers  = (const float*)d_in[1];
    const float* init_scales   = (const float*)d_in[2];
    const float* init_weights  = (const float*)d_in[3];
    const float* prior_p_param = (const float*)d_in[4];
    const float* weights_param = (const float*)d_in[5];
    const float* blend         = (const float*)d_in[6];
    const float* noise         = (const float*)d_in[7];

    float* out       = (float*)d_out;
    float* out_g     = out;                                    // [B, L, K]
    float* out_w     = out_g + (size_t)Bn * Ln * Kn;           // [B, K]
    float* out_mu    = out_w + (size_t)Bn * Kn;                // [B, K]
    float* out_sigma = out_mu + (size_t)Bn * Kn;               // [B, K]

    dim3 grid(Bn / 8);   // 4 waves per block, 2 rows per wave
    dim3 block(256);
    hipLaunchKernelGGL(em_kernel, grid, block, 0, stream,
                       windows, init_centers, init_scales, init_weights,
                       prior_p_param, weights_param, blend, noise,
                       out_g, out_w, out_mu, out_sigma);
}

// Round 7
// 194.831 us; speedup vs baseline: 1.1154x; 1.0182x over previous
//
#include <hip/hip_runtime.h>
#include <math.h>

// NormalMixtureEM: B=16384 rows, L=512, K=4, 5 EM iters. One wave per row.
// R11 (revert to verified R6 single-row + safe trims; dual-row abandoned):
//  - Budget model corrected: gfx950 compiler arch-VGPR budget is 256, so
//    __launch_bounds__(256,N) caps VGPRs at 256/N: (256,8)->32 (R7 spill),
//    (256,4)->64 (R8 dual-row spill), (256,2)->128 (R10 fit but occupancy
//    28% + partial-line write inflation). Single-row at 48 VGPR under the
//    (256,4) cap of 64 is the sweet spot.
//  - Trim 1: M-step uses v_rsq: invse = rsq(var+EPS), sigma = (var+EPS)*rsq
//    (one fewer trans op and a shorter serial chain than sqrt->add->rcp;
//    differs from reference by 1e-8 relative -- invisible at absmax 4e-3).
//  - Trim 2: hoisted g-store base (constant offsets, no per-store index math).
//  - Trim 3: init reduction merged into one wred6 (was 2x wred3 + junk slot).
//  - Kept: lane-per-component M-step (kk=lane&3), DPP quad_perm intra-quad
//    shuffles, ratio softmax vs component 3 (3 exp2 + 1 rcp per sample),
//    wred interleaved DPP reductions, float4 loads, iteration-invariant
//    W{0,1,2} totals deriving component 3's moments.

constexpr int Bn = 16384;
constexpr int Ln = 512;
constexpr int Kn = 4;
constexpr int NITER = 5;
constexpr float EPSf = 1e-8f;
constexpr float NOISEf = 0.01f;
constexpr float LOG2E = 1.4426950408889634f;

__device__ __forceinline__ float frcp(float v) { return __builtin_amdgcn_rcpf(v); }
__device__ __forceinline__ float frsq(float v) { return __builtin_amdgcn_rsqf(v); }
__device__ __forceinline__ float fexp2(float v) { return __builtin_amdgcn_exp2f(v); }

__device__ __forceinline__ float rlane(float v, int l) {
    return __int_as_float(__builtin_amdgcn_readlane(__float_as_int(v), l));
}

// DPP helpers (VALU pipe; compiler inserts required hazard wait-states).
// quad_perm ctrl byte = sel0 | sel1<<2 | sel2<<4 | sel3<<6.
template <int CTRL>
__device__ __forceinline__ float dpp_mov(float v) {
    return __int_as_float(
        __builtin_amdgcn_update_dpp(0, __float_as_int(v), CTRL, 0xF, 0xF, true));
}
template <int CTRL>
__device__ __forceinline__ float dpp_add(float v) {
    return v + dpp_mov<CTRL>(v);
}

// Interleaved full-wave sums via DPP adds; totals land in lane 63.
// Round-robin keeps same-register DPP reads >=3 instrs apart (hazard-free);
// s_nop 1 guards the asm boundaries.
#define WRED3_STEP(ctrl) \
    "v_add_f32_dpp %0, %0, %0 " ctrl " row_mask:0xf bank_mask:0xf bound_ctrl:0\n\t" \
    "v_add_f32_dpp %1, %1, %1 " ctrl " row_mask:0xf bank_mask:0xf bound_ctrl:0\n\t" \
    "v_add_f32_dpp %2, %2, %2 " ctrl " row_mask:0xf bank_mask:0xf bound_ctrl:0\n\t"

__device__ __forceinline__ void wred3(float& a, float& b, float& c) {
    asm volatile(
        "s_nop 1\n\t"
        WRED3_STEP("row_shr:1")
        WRED3_STEP("row_shr:2")
        WRED3_STEP("row_shr:4")
        WRED3_STEP("row_shr:8")
        WRED3_STEP("row_bcast:15")
        WRED3_STEP("row_bcast:31")
        "s_nop 1"
        : "+v"(a), "+v"(b), "+v"(c));
}

#define WRED6_STEP(ctrl) \
    "v_add_f32_dpp %0, %0, %0 " ctrl " row_mask:0xf bank_mask:0xf bound_ctrl:0\n\t" \
    "v_add_f32_dpp %1, %1, %1 " ctrl " row_mask:0xf bank_mask:0xf bound_ctrl:0\n\t" \
    "v_add_f32_dpp %2, %2, %2 " ctrl " row_mask:0xf bank_mask:0xf bound_ctrl:0\n\t" \
    "v_add_f32_dpp %3, %3, %3 " ctrl " row_mask:0xf bank_mask:0xf bound_ctrl:0\n\t" \
    "v_add_f32_dpp %4, %4, %4 " ctrl " row_mask:0xf bank_mask:0xf bound_ctrl:0\n\t" \
    "v_add_f32_dpp %5, %5, %5 " ctrl " row_mask:0xf bank_mask:0xf bound_ctrl:0\n\t"

__device__ __forceinline__ void wred6(float& a, float& b, float& c,
                                      float& d, float& e, float& f) {
    asm volatile(
        "s_nop 1\n\t"
        WRED6_STEP("row_shr:1")
        WRED6_STEP("row_shr:2")
        WRED6_STEP("row_shr:4")
        WRED6_STEP("row_shr:8")
        WRED6_STEP("row_bcast:15")
        WRED6_STEP("row_bcast:31")
        "s_nop 1"
        : "+v"(a), "+v"(b), "+v"(c), "+v"(d), "+v"(e), "+v"(f));
}

struct RowState {
    float x[8], xx[8], wl[8];
    float muk, wk, invsek, sigk;   // per-lane component k = lane&3
    float blender, prior_p;
    float bm, bv;                  // (1-blender)*mean, (1-blender)*prior_var
    float W0, W1, W2;              // iteration-invariant: sum_l wl*{1, x, x^2}
};

template <bool LAST>
__device__ __forceinline__ void em_iter(RowState& st, float* __restrict__ gp0,
                                        int kk) {
    // Per-lane (k = kk) quadratic coefficients in log2 domain.
    float is2 = st.invsek * st.invsek;
    float lw2 = __log2f((st.wk + EPSf) * st.invsek);
    float Ak = (-0.5f * LOG2E) * is2;
    float Bk = (LOG2E * st.muk) * is2;
    float Ck = fmaf((-0.5f * LOG2E) * (st.muk * st.muk), is2, lw2);
    // Deltas vs component 3 (quad-lane 3) via DPP broadcast; lane kk==3 -> 0.
    float dAl = Ak - dpp_mov<0xFF>(Ak);
    float dBl = Bk - dpp_mov<0xFF>(Bk);
    float dCl = Ck - dpp_mov<0xFF>(Ck);
    // Gather the 9 wave-uniform coefficients into SGPRs.
    float a0 = rlane(dAl, 0), a1 = rlane(dAl, 1), a2 = rlane(dAl, 2);
    float b0 = rlane(dBl, 0), b1 = rlane(dBl, 1), b2 = rlane(dBl, 2);
    float c0 = rlane(dCl, 0), c1 = rlane(dCl, 1), c2 = rlane(dCl, 2);

    float S00 = 0, S01 = 0, S02 = 0;
    float S10 = 0, S11 = 0, S12 = 0;
    float S20 = 0, S21 = 0, S22 = 0;
#pragma unroll
    for (int j = 0; j < 8; ++j) {
        float lm0 = fmaf(a0, st.xx[j], fmaf(b0, st.x[j], c0));
        float lm1 = fmaf(a1, st.xx[j], fmaf(b1, st.x[j], c1));
        float lm2 = fmaf(a2, st.xx[j], fmaf(b2, st.x[j], c2));
        float r0 = fexp2(lm0);
        float r1 = fexp2(lm1);
        float r2 = fexp2(lm2);
        float esum = (r0 + r1) + (r2 + 1.f);   // component 3's ratio is 1
        float inv = frcp(esum);
        float wls = st.wl[j] * inv;
        float wlsx = wls * st.x[j];
        float wlsxx = wls * st.xx[j];
        S00 = fmaf(r0, wls, S00); S10 = fmaf(r0, wlsx, S10); S20 = fmaf(r0, wlsxx, S20);
        S01 = fmaf(r1, wls, S01); S11 = fmaf(r1, wlsx, S11); S21 = fmaf(r1, wlsxx, S21);
        S02 = fmaf(r2, wls, S02); S12 = fmaf(r2, wlsx, S12); S22 = fmaf(r2, wlsxx, S22);
        if (LAST) {
            float4 g4 = make_float4(r0 * inv, r1 * inv, r2 * inv, inv);
            if (j < 4) *(float4*)(gp0 + 4 * j) = g4;
            else       *(float4*)(gp0 + 1024 + 4 * (j - 4)) = g4;
        }
    }

    // Wave-reduce the 9 moments; totals in lane 63 -> SGPRs.
    wred6(S00, S10, S20, S01, S11, S21);
    wred3(S02, S12, S22);
    float s00 = rlane(S00, 63), s10 = rlane(S10, 63), s20 = rlane(S20, 63);
    float s01 = rlane(S01, 63), s11 = rlane(S11, 63), s21 = rlane(S21, 63);
    float s02 = rlane(S02, 63), s12 = rlane(S12, 63), s22 = rlane(S22, 63);
    // Component 3 from iteration-invariant totals (sum_k g = 1).
    float d0 = st.W0 - s00 - s01 - s02;
    float d1 = st.W1 - s10 - s11 - s12;
    float d2 = st.W2 - s20 - s21 - s22;
    // Per-lane selection of this lane's component moments.
    float vT0 = (kk == 0) ? s00 : (kk == 1) ? s01 : (kk == 2) ? s02 : d0;
    float vT1 = (kk == 0) ? s10 : (kk == 1) ? s11 : (kk == 2) ? s12 : d1;
    float vT2 = (kk == 0) ? s20 : (kk == 1) ? s21 : (kk == 2) ? s22 : d2;

    // M-step, one component per lane. Single-pass moments:
    // sum wg*(x-mu)^2 = S2 - 2*mu*S1 + mu^2*S0.
    float sg = fmaxf(vT0, EPSf);
    float rsg = frcp(sg);
    float mun = fmaf(st.blender, vT1 * rsg, st.bm);
    float num = fmaf(mun * mun, vT0, fmaf(-2.f * mun, vT1, vT2));
    float dv = fmaxf(num * rsg, 0.f);
    float var = fmaf(st.blender, dv, st.bv) + EPSf;
    float r = frsq(var);            // invse = rsq(var+eps); sigma = var*r
    st.muk = mun;
    st.sigk = var * r;
    st.invsek = r;
    float wn = sg + st.prior_p;
    // wsum over the 4-lane group via DPP quad_perm butterfly (VALU pipe).
    float ws = dpp_add<0xB1>(wn);   // quad_perm:[1,0,3,2]  (xor 1)
    ws = dpp_add<0x4E>(ws);         // quad_perm:[2,3,0,1]  (xor 2)
    st.wk = wn * frcp(ws);
}

__global__ __launch_bounds__(256, 4) void em_kernel(
    const float* __restrict__ windows,
    const float* __restrict__ centers,
    const float* __restrict__ scales,
    const float* __restrict__ iweights,
    const float* __restrict__ prior_p_param,
    const float* __restrict__ weights_param,
    const float* __restrict__ blend,
    const float* __restrict__ noise,
    float* __restrict__ out_g,
    float* __restrict__ out_w,
    float* __restrict__ out_mu,
    float* __restrict__ out_sigma)
{
    const int lane = threadIdx.x & 63;
    const int kk = lane & 3;
    const int b = blockIdx.x * 4 + (threadIdx.x >> 6);

    RowState st;
    const float* __restrict__ xr = windows + (size_t)b * Ln;
    const float4 q0 = *(const float4*)(xr + 4 * lane);
    const float4 q1 = *(const float4*)(xr + 256 + 4 * lane);
    st.x[0] = q0.x; st.x[1] = q0.y; st.x[2] = q0.z; st.x[3] = q0.w;
    st.x[4] = q1.x; st.x[5] = q1.y; st.x[6] = q1.z; st.x[7] = q1.w;

    const float4 e0 = *(const float4*)(weights_param + 4 * lane);
    const float4 e1 = *(const float4*)(weights_param + 256 + 4 * lane);
    st.wl[0] = __expf(e0.x); st.wl[1] = __expf(e0.y);
    st.wl[2] = __expf(e0.z); st.wl[3] = __expf(e0.w);
    st.wl[4] = __expf(e1.x); st.wl[5] = __expf(e1.y);
    st.wl[6] = __expf(e1.z); st.wl[7] = __expf(e1.w);

    // Row stats + iteration-invariant weighted totals.
    float s = 0.f, ss = 0.f, w0 = 0.f, w1 = 0.f, w2 = 0.f;
#pragma unroll
    for (int j = 0; j < 8; ++j) {
        st.xx[j] = st.x[j] * st.x[j];
        s += st.x[j];
        ss += st.xx[j];
        w0 += st.wl[j];
        w1 = fmaf(st.wl[j], st.x[j], w1);
        w2 = fmaf(st.wl[j], st.xx[j], w2);
    }
    float junk = 0.f;
    wred6(s, ss, w0, w1, w2, junk);
    s = rlane(s, 63);
    ss = rlane(ss, 63);
    st.W0 = rlane(w0, 63);
    st.W1 = rlane(w1, 63);
    st.W2 = rlane(w2, 63);

    const float mean = s * (1.0f / Ln);
    const float var1 = fmaxf((ss - s * mean) * (1.0f / (Ln - 1)), 0.f);
    const float sd = sqrtf(var1);

    st.prior_p = 1.f / (1.f + __expf(-prior_p_param[0]));
    st.blender = 1.f / (1.f + __expf(-blend[0]));
    const float omb = 1.f - st.blender;
    st.bm = omb * mean;
    st.bv = omb * var1;

    // Per-lane component init (k = kk).
    st.muk = fmaf(centers[kk], sd, mean) + noise[(size_t)b * 4 + kk] * sd * NOISEf;
    float sg0 = fabsf(scales[kk]) * sd;
    st.sigk = sg0;
    st.wk = iweights[kk];
    st.invsek = frcp(sg0 + EPSf);

    // Hoisted g-store bases: sample (lane,j<4) -> l = 4*lane+j,
    // (lane,j>=4) -> l = 256+4*lane+(j-4); float offset = 4*l.
    float* gp0 = out_g + (size_t)b * (Ln * Kn) + 16 * lane;

    for (int it = 0; it < NITER - 1; ++it)
        em_iter<false>(st, gp0, kk);
    em_iter<true>(st, gp0, kk);

    if (lane < 4) {
        out_w[(size_t)b * 4 + lane]     = st.wk;
        out_mu[(size_t)b * 4 + lane]    = st.muk;
        out_sigma[(size_t)b * 4 + lane] = st.sigk;
    }
}

extern "C" void kernel_launch(void* const* d_in, const int* in_sizes, int n_in,
                              void* d_out, int out_size, void* d_ws, size_t ws_size,
                              hipStream_t stream) {
    const float* windows       = (const float*)d_in[0];
    const float* init_centers  = (const float*)d_in[1];
    const float* init_scales   = (const float*)d_in[2];
    const float* init_weights  = (const float*)d_in[3];
    const float* prior_p_param = (const float*)d_in[4];
    const float* weights_param = (const float*)d_in[5];
    const float* blend         = (const float*)d_in[6];
    const float* noise         = (const float*)d_in[7];

    float* out       = (float*)d_out;
    float* out_g     = out;                                    // [B, L, K]
    float* out_w     = out_g + (size_t)Bn * Ln * Kn;           // [B, K]
    float* out_mu    = out_w + (size_t)Bn * Kn;                // [B, K]
    float* out_sigma = out_mu + (size_t)Bn * Kn;               // [B, K]

    dim3 grid(Bn / 4);   // 4 waves per block, 1 wave per row
    dim3 block(256);
    hipLaunchKernelGGL(em_kernel, grid, block, 0, stream,
                       windows, init_centers, init_scales, init_weights,
                       prior_p_param, weights_param, blend, noise,
                       out_g, out_w, out_mu, out_sigma);
}